// Round 1
// baseline (23617.349 us; speedup 1.0000x reference)
//
#include <hip/hip_runtime.h>
#include <cstdint>
#include <cstddef>

#define B_ 1024
#define T_ 96
#define I_ 256
#define H_ 1024

typedef unsigned short u16;
typedef __attribute__((ext_vector_type(8))) short short8;
typedef __attribute__((ext_vector_type(4))) float f32x4;
typedef __attribute__((ext_vector_type(4))) unsigned int u32x4;

__device__ __forceinline__ float bf2f(u16 u) {
  union { unsigned int i; float f; } v;
  v.i = ((unsigned int)u) << 16;
  return v.f;
}
__device__ __forceinline__ u16 f2bf(float f) {
  union { float f; unsigned int i; } v;
  v.f = f;
  unsigned int u = v.i;
  return (u16)((u + 0x7FFFu + ((u >> 16) & 1u)) >> 16);
}

// ---------------------------------------------------------------------------
// dtype detector: bf16 N(0,1) data has no u16 with exponent field >= 0xC0;
// fp32 data read as u16 has ~25% such words in the low halves. 0=bf16, 1=fp32.
__global__ void detect_dtype(const u16* __restrict__ xs, int* __restrict__ flag) {
  __shared__ int cnt;
  if (threadIdx.x == 0) cnt = 0;
  __syncthreads();
  int c = 0;
  for (int i = threadIdx.x; i < 8192; i += 256) {
    int e = (xs[i] >> 7) & 0xFF;
    if (e >= 0xC0) ++c;
  }
  atomicAdd(&cnt, c);
  __syncthreads();
  if (threadIdx.x == 0) *flag = (cnt > 32) ? 1 : 0;
}

__global__ void zero_f32(float* __restrict__ p, int n) {
  int i = blockIdx.x * 256 + threadIdx.x;
  if (i < n) p[i] = 0.f;
}

// weight transpose [K][N] -> hi/lo bf16 planes [N][K]; input dtype per flag
__global__ void transpose_w(const void* __restrict__ W, u16* __restrict__ Th,
                            u16* __restrict__ Tl, int K, int N,
                            const int* __restrict__ dflag) {
  __shared__ float tile[32][33];
  const int f = *dflag;
  int n0 = blockIdx.x * 32, k0 = blockIdx.y * 32;
  int tx = threadIdx.x, ty = threadIdx.y;
#pragma unroll
  for (int i = ty; i < 32; i += 8) {
    size_t o = (size_t)(k0 + i) * N + n0 + tx;
    tile[i][tx] = f ? ((const float*)W)[o] : bf2f(((const u16*)W)[o]);
  }
  __syncthreads();
#pragma unroll
  for (int i = ty; i < 32; i += 8) {
    float v = tile[tx][i];
    u16 h = f2bf(v);
    size_t o = (size_t)(n0 + i) * K + k0 + tx;
    Th[o] = h;
    Tl[o] = f2bf(v - bf2f(h));
  }
}

// xin = x*mask+noise, fp32, vectorized 8/thread
__global__ void make_xin(const void* __restrict__ x, const void* __restrict__ m,
                         const void* __restrict__ nz, float* __restrict__ o,
                         const int* __restrict__ dflag) {
  const int f = *dflag;
  size_t i = ((size_t)blockIdx.x * 256 + threadIdx.x) * 8;
  float v[8];
  if (f) {
    const float* xp = (const float*)x + i;
    const float* mp = (const float*)m + i;
    const float* np = (const float*)nz + i;
    f32x4 x0 = *(const f32x4*)xp, x1 = *(const f32x4*)(xp + 4);
    f32x4 m0 = *(const f32x4*)mp, m1 = *(const f32x4*)(mp + 4);
    f32x4 n0 = *(const f32x4*)np, n1 = *(const f32x4*)(np + 4);
#pragma unroll
    for (int j = 0; j < 4; ++j) {
      v[j] = x0[j] * m0[j] + n0[j];
      v[j + 4] = x1[j] * m1[j] + n1[j];
    }
  } else {
    union { u32x4 q; u16 s[8]; } ux, um, un;
    ux.q = *(const u32x4*)((const u16*)x + i);
    um.q = *(const u32x4*)((const u16*)m + i);
    un.q = *(const u32x4*)((const u16*)nz + i);
#pragma unroll
    for (int j = 0; j < 8; ++j) v[j] = bf2f(ux.s[j]) * bf2f(um.s[j]) + bf2f(un.s[j]);
  }
  f32x4 o0, o1;
#pragma unroll
  for (int j = 0; j < 4; ++j) { o0[j] = v[j]; o1[j] = v[j + 4]; }
  *(f32x4*)(o + i) = o0;
  *(f32x4*)(o + i + 4) = o1;
}

// ---------------------------------------------------------------------------
// Split MFMA GEMM.  Block tile 64 x BN, 256 threads (4 waves 2x2), 16x16x32
// bf16 MFMA, BK=32, 2-deep register prefetch (two named reg sets; all
// compile-time indexed).  A staged as hi/lo bf16 planes; B pre-transposed
// hi/lo planes [N][K] (lo skipped when inputs are bf16).
// AH (k<K0):  0 = external dtype-per-flag (A0, lda0, aoff0)
//             1 = fp32 (A0, lda0, aoff0)
//             2 = Beta(*)Hb fused: av = Bet[row*bstr+k] * A0[row*H_+k]
// AI (k>=K0): 0 = none ; 1 = fp32 (Ax,lda1,aoff1) ; 2 = x*mask+noise fused
// EPI: 0 = store p+bias                     (dst0, dstr0)
//      2 = r/mu gates; RH = sig*Beta*Hb     (dst0=RH, dst1=MU, src0=Hb)
//      3 = h = (1-mu)*Beta*Hb + mu*tanh     (dst0=Hb, src0=Hb, src1=MU)
//      5 = reg: v=tanh(p+b) -> Xt + out     (dst0=Xt, dst1=out, tstep)
//      7 = beta store: exp(-relu(p+b))      (dst0, dstr0)
template <int BN, int EPI, int AH, int AI>
__global__ __launch_bounds__(256) void gemm_k(
    const void* __restrict__ A0, int lda0, int aoff0, int K0,
    const void* __restrict__ Ax, const void* __restrict__ Am,
    const void* __restrict__ An, int lda1, int aoff1,
    const float* Bet, int bstr,
    const u16* __restrict__ BTh, const u16* __restrict__ BTl, int K,
    const void* __restrict__ bias0, const void* __restrict__ bias1,
    const float* src0, const float* __restrict__ src1,
    float* dst0, int dstr0, void* __restrict__ dst1, int tstep,
    const int* __restrict__ dflag) {
  __shared__ __align__(16) u16 As_hi[64][40];
  __shared__ __align__(16) u16 As_lo[64][40];
  __shared__ __align__(16) u16 Bs_hi[BN][40];
  __shared__ __align__(16) u16 Bs_lo[BN][40];

  const int f = *dflag;                 // uniform: 0=bf16 inputs, 1=fp32
  const bool alo = (AH != 0) || f;      // A-lo plane active?

  const int tid = threadIdx.x;
  const int m0 = blockIdx.y * 64;
  const int n0 = blockIdx.x * BN;

  const int w = tid >> 6;
  const int lane = tid & 63;
  const int wx = w & 1, wy = w >> 1;
  const int lr = lane & 15, q = lane >> 4;
  constexpr int NB = BN / 32;

  f32x4 acc[2][NB];
#pragma unroll
  for (int mb = 0; mb < 2; ++mb)
#pragma unroll
    for (int nb = 0; nb < NB; ++nb)
      acc[mb][nb] = (f32x4){0.f, 0.f, 0.f, 0.f};

  const int ar = tid >> 2, ac8 = (tid & 3) * 8;
  const int bn = (BN == 128) ? (tid >> 1) : (tid >> 2);
  const int bc = (BN == 128) ? ((tid & 1) * 16) : ((tid & 3) * 8);

  auto load_chunk = [&](int kc, float (&av)[8], u32x4 (&pbh)[2], u32x4 (&pbl)[2]) {
    // ---- A operand -> av[8] fp32 ----
    if (AI == 0 || kc < K0) {
      if (AH == 0) {
        size_t o = (size_t)(m0 + ar) * lda0 + aoff0 + kc + ac8;
        if (f) {
          f32x4 t0 = *(const f32x4*)((const float*)A0 + o);
          f32x4 t1 = *(const f32x4*)((const float*)A0 + o + 4);
#pragma unroll
          for (int j = 0; j < 4; ++j) { av[j] = t0[j]; av[j + 4] = t1[j]; }
        } else {
          union { u32x4 v; u16 s[8]; } t;
          t.v = *(const u32x4*)((const u16*)A0 + o);
#pragma unroll
          for (int j = 0; j < 8; ++j) av[j] = bf2f(t.s[j]);
        }
      } else if (AH == 1) {
        size_t o = (size_t)(m0 + ar) * lda0 + aoff0 + kc + ac8;
        f32x4 t0 = *(const f32x4*)((const float*)A0 + o);
        f32x4 t1 = *(const f32x4*)((const float*)A0 + o + 4);
#pragma unroll
        for (int j = 0; j < 4; ++j) { av[j] = t0[j]; av[j + 4] = t1[j]; }
      } else {  // AH==2: Beta * Hb
        size_t ob = (size_t)(m0 + ar) * bstr + kc + ac8;
        size_t oh = (size_t)(m0 + ar) * H_ + kc + ac8;
        f32x4 b0 = *(const f32x4*)(Bet + ob);
        f32x4 b1 = *(const f32x4*)(Bet + ob + 4);
        f32x4 h0 = *(const f32x4*)((const float*)A0 + oh);
        f32x4 h1 = *(const f32x4*)((const float*)A0 + oh + 4);
#pragma unroll
        for (int j = 0; j < 4; ++j) {
          av[j] = b0[j] * h0[j];
          av[j + 4] = b1[j] * h1[j];
        }
      }
    } else {
      int kk = kc - K0;
      size_t o = (size_t)(m0 + ar) * lda1 + aoff1 + kk + ac8;
      if (AI == 1) {
        f32x4 t0 = *(const f32x4*)((const float*)Ax + o);
        f32x4 t1 = *(const f32x4*)((const float*)Ax + o + 4);
#pragma unroll
        for (int j = 0; j < 4; ++j) { av[j] = t0[j]; av[j + 4] = t1[j]; }
      } else {  // AI==2: x*mask+noise fused
        if (f) {
          const float* xp = (const float*)Ax + o;
          const float* mp = (const float*)Am + o;
          const float* np = (const float*)An + o;
          f32x4 x0 = *(const f32x4*)xp, x1 = *(const f32x4*)(xp + 4);
          f32x4 m0v = *(const f32x4*)mp, m1v = *(const f32x4*)(mp + 4);
          f32x4 n0v = *(const f32x4*)np, n1v = *(const f32x4*)(np + 4);
#pragma unroll
          for (int j = 0; j < 4; ++j) {
            av[j] = x0[j] * m0v[j] + n0v[j];
            av[j + 4] = x1[j] * m1v[j] + n1v[j];
          }
        } else {
          union { u32x4 v; u16 s[8]; } ux, um, un;
          ux.v = *(const u32x4*)((const u16*)Ax + o);
          um.v = *(const u32x4*)((const u16*)Am + o);
          un.v = *(const u32x4*)((const u16*)An + o);
#pragma unroll
          for (int j = 0; j < 8; ++j)
            av[j] = bf2f(ux.s[j]) * bf2f(um.s[j]) + bf2f(un.s[j]);
        }
      }
    }
    // ---- B operand ----
    const u16* Bph = BTh + (size_t)(n0 + bn) * K + kc + bc;
    pbh[0] = *(const u32x4*)Bph;
    if (BN == 128) pbh[1] = *(const u32x4*)(Bph + 8);
    if (f) {
      const u16* Bpl = BTl + (size_t)(n0 + bn) * K + kc + bc;
      pbl[0] = *(const u32x4*)Bpl;
      if (BN == 128) pbl[1] = *(const u32x4*)(Bpl + 8);
    }
  };

  auto drain = [&](float (&av)[8], u32x4 (&pbh)[2], u32x4 (&pbl)[2]) {
    union { u16 s[8]; u32x4 v; } ph, pl;
#pragma unroll
    for (int j = 0; j < 8; ++j) {
      u16 h = f2bf(av[j]);
      ph.s[j] = h;
      pl.s[j] = f2bf(av[j] - bf2f(h));
    }
    *(u32x4*)&As_hi[ar][ac8] = ph.v;
    if (alo) *(u32x4*)&As_lo[ar][ac8] = pl.v;
    *(u32x4*)&Bs_hi[bn][bc] = pbh[0];
    if (BN == 128) *(u32x4*)&Bs_hi[bn][bc + 8] = pbh[1];
    if (f) {
      *(u32x4*)&Bs_lo[bn][bc] = pbl[0];
      if (BN == 128) *(u32x4*)&Bs_lo[bn][bc + 8] = pbl[1];
    }
  };

  auto mfma_phase = [&]() {
    short8 ah[2], al[2];
#pragma unroll
    for (int mb = 0; mb < 2; ++mb) {
      ah[mb] = *(const short8*)&As_hi[wy * 32 + mb * 16 + lr][q * 8];
      if (alo) al[mb] = *(const short8*)&As_lo[wy * 32 + mb * 16 + lr][q * 8];
    }
#pragma unroll
    for (int nb = 0; nb < NB; ++nb) {
      short8 bh = *(const short8*)&Bs_hi[wx * (BN / 2) + nb * 16 + lr][q * 8];
#pragma unroll
      for (int mb = 0; mb < 2; ++mb) {
        acc[mb][nb] = __builtin_amdgcn_mfma_f32_16x16x32_bf16(ah[mb], bh, acc[mb][nb], 0, 0, 0);
        if (alo)
          acc[mb][nb] = __builtin_amdgcn_mfma_f32_16x16x32_bf16(al[mb], bh, acc[mb][nb], 0, 0, 0);
      }
      if (f) {
        short8 bl = *(const short8*)&Bs_lo[wx * (BN / 2) + nb * 16 + lr][q * 8];
#pragma unroll
        for (int mb = 0; mb < 2; ++mb)
          acc[mb][nb] = __builtin_amdgcn_mfma_f32_16x16x32_bf16(ah[mb], bl, acc[mb][nb], 0, 0, 0);
      }
    }
  };

  // 2-deep prefetch: two named register sets, compile-time indexed.
  float av0[8], av1[8];
  u32x4 bh0[2], bl0[2], bh1[2], bl1[2];
  load_chunk(0, av0, bh0, bl0);
  if (32 < K) load_chunk(32, av1, bh1, bl1);
  for (int kc = 0; kc < K; kc += 64) {
    drain(av0, bh0, bl0);
    __syncthreads();
    if (kc + 64 < K) load_chunk(kc + 64, av0, bh0, bl0);
    mfma_phase();
    __syncthreads();
    if (kc + 32 < K) {
      drain(av1, bh1, bl1);
      __syncthreads();
      if (kc + 96 < K) load_chunk(kc + 96, av1, bh1, bl1);
      mfma_phase();
      __syncthreads();
    }
  }

  auto bget = [&](const void* b, int c) -> float {
    return f ? ((const float*)b)[c] : bf2f(((const u16*)b)[c]);
  };

  // epilogue: D row = q*4+r, col = lane&15 (m89-verified C/D layout)
#pragma unroll
  for (int mb = 0; mb < 2; ++mb) {
#pragma unroll
    for (int nb = 0; nb < NB; ++nb) {
#pragma unroll
      for (int r = 0; r < 4; ++r) {
        int row = m0 + wy * 32 + mb * 16 + q * 4 + r;
        int col = n0 + wx * (BN / 2) + nb * 16 + lr;
        float p = acc[mb][nb][r];
        if (EPI == 0) {
          dst0[(size_t)row * dstr0 + col] = p + bget(bias0, col);
        } else if (EPI == 2) {
          if (col < H_) {
            float rr = 1.f / (1.f + expf(-(p + bget(bias0, col))));
            dst0[(size_t)row * H_ + col] =
                rr * Bet[(size_t)row * bstr + col] * src0[(size_t)row * H_ + col];
          } else {
            int c = col - H_;
            float mu = 1.f / (1.f + expf(-(p + bget(bias1, c))));
            ((float*)dst1)[(size_t)row * H_ + c] = mu;
          }
        } else if (EPI == 3) {
          size_t ix = (size_t)row * H_ + col;
          float hh = tanhf(p + bget(bias0, col));
          float mu = src1[ix];
          float hs = Bet[(size_t)row * bstr + col] * src0[ix];
          dst0[ix] = (1.f - mu) * hs + mu * hh;
        } else if (EPI == 5) {
          float v = tanhf(p + bget(bias0, col));
          dst0[(size_t)row * dstr0 + col] = v;
          size_t ox = (size_t)row * (T_ * I_) + (size_t)tstep * I_ + col;
          if (f) ((float*)dst1)[ox] = v;
          else ((u16*)dst1)[ox] = f2bf(v);
        } else if (EPI == 7) {
          dst0[(size_t)row * dstr0 + col] = expf(-fmaxf(p + bget(bias0, col), 0.f));
        }
      }
    }
  }
}

// ---------------------------------------------------------------------------
extern "C" void kernel_launch(void* const* d_in, const int* in_sizes, int n_in,
                              void* d_out, int out_size, void* d_ws, size_t ws_size,
                              hipStream_t stream) {
  const void* x_ = d_in[0];
  const void* mask_ = d_in[1];
  const void* delta_ = d_in[2];
  const void* noise_ = d_in[3];
  const void* eWtd = d_in[4];
  const void* ebtd = d_in[5];
  const void* eWr = d_in[6];
  const void* ebr = d_in[7];
  const void* eWmu = d_in[8];
  const void* ebmu = d_in[9];
  const void* eWhh = d_in[10];
  const void* ebhh = d_in[11];
  const void* zW = d_in[12];
  const void* zb = d_in[13];
  const void* diW = d_in[14];
  const void* dib = d_in[15];
  const void* dWtd = d_in[16];
  const void* dbtd = d_in[17];
  const void* dWr = d_in[18];
  const void* dbr = d_in[19];
  const void* dWmu = d_in[20];
  const void* dbmu = d_in[21];
  const void* dWhh = d_in[22];
  const void* dbhh = d_in[23];
  const void* rW = d_in[24];
  const void* rb = d_in[25];

  char* ws = (char*)d_ws;
  size_t off = 0;
  auto alloc = [&](size_t bytes) -> char* {
    char* p = ws + off;
    off = (off + bytes + 255) & ~(size_t)255;
    return p;
  };
  int* dflag = (int*)alloc(256);
  float* Hb = (float*)alloc((size_t)B_ * H_ * 4);
  float* RH = (float*)alloc((size_t)B_ * H_ * 4);   // also reused as Z
  float* MUb = (float*)alloc((size_t)B_ * H_ * 4);
  float* Xt = (float*)alloc((size_t)B_ * I_ * 4);
  float* Beta1 = (float*)alloc((size_t)B_ * H_ * 4);  // per-step beta fallback
  auto wpair = [&](size_t elems, u16** lo) -> u16* {
    u16* hi = (u16*)alloc(elems * 2);
    *lo = (u16*)alloc(elems * 2);
    return hi;
  };
  u16 *eWtdL, *eWrmL, *eWhhL, *zWL, *diWL, *dWtdL, *dWrmL, *dWhhL, *rWL;
  u16* eWtdT = wpair((size_t)H_ * I_, &eWtdL);
  u16* eWrmT = wpair((size_t)2 * H_ * (H_ + I_), &eWrmL);
  u16* eWhhT = wpair((size_t)H_ * (H_ + I_), &eWhhL);
  u16* zWT = wpair((size_t)H_ * H_, &zWL);
  u16* diWT = wpair((size_t)I_ * H_, &diWL);
  u16* dWtdT = wpair((size_t)H_ * I_, &dWtdL);
  u16* dWrmT = wpair((size_t)2 * H_ * (H_ + I_), &dWrmL);
  u16* dWhhT = wpair((size_t)H_ * (H_ + I_), &dWhhL);
  u16* rWT = wpair((size_t)I_ * H_, &rWL);
  // workspace-gated large buffers
  float* Xin = (float*)alloc((size_t)B_ * T_ * I_ * 4);     // ~100.7 MB
  size_t xin_end = off;
  float* BetaT = (float*)alloc((size_t)B_ * T_ * H_ * 4);   // ~402.7 MB
  size_t full_end = off;
  const bool xinT = ws_size >= xin_end;
  const bool fullT = ws_size >= full_end;

  // prolog
  detect_dtype<<<1, 256, 0, stream>>>((const u16*)x_, dflag);
  zero_f32<<<(B_ * H_) / 256, 256, 0, stream>>>(Hb, B_ * H_);

  auto tr = [&](const void* W, u16* Th, u16* Tl, int K, int N) {
    transpose_w<<<dim3(N / 32, K / 32), dim3(32, 8), 0, stream>>>(W, Th, Tl, K, N, dflag);
  };
  tr(eWtd, eWtdT, eWtdL, I_, H_);
  tr(eWr, eWrmT, eWrmL, H_ + I_, H_);
  tr(eWmu, eWrmT + (size_t)H_ * (H_ + I_), eWrmL + (size_t)H_ * (H_ + I_), H_ + I_, H_);
  tr(eWhh, eWhhT, eWhhL, H_ + I_, H_);
  tr(zW, zWT, zWL, H_, H_);
  tr(diW, diWT, diWL, H_, I_);
  tr(dWtd, dWtdT, dWtdL, I_, H_);
  tr(dWr, dWrmT, dWrmL, H_ + I_, H_);
  tr(dWmu, dWrmT + (size_t)H_ * (H_ + I_), dWrmL + (size_t)H_ * (H_ + I_), H_ + I_, H_);
  tr(dWhh, dWhhT, dWhhL, H_ + I_, H_);
  tr(rW, rWT, rWL, H_, I_);

  if (xinT)
    make_xin<<<(B_ * T_ * I_) / (256 * 8), 256, 0, stream>>>(x_, mask_, noise_, Xin, dflag);

  const int GY = B_ / 64;  // 16

  // beta precompute for ALL t in one GEMM: rows m=b*T+t (delta is [B][T][I]
  // row-major so lda=I_, aoff=0), output BetaT[b*T+t][H] = [B][T][H].
  auto beta_all = [&](const u16* Th, const u16* Tl, const void* bias) {
    gemm_k<128, 7, 0, 0><<<dim3(H_ / 128, (B_ * T_) / 64), 256, 0, stream>>>(
        delta_, I_, 0, I_, nullptr, nullptr, nullptr, 0, 0, nullptr, 0,
        Th, Tl, I_, bias, nullptr, nullptr, nullptr, BetaT, H_, nullptr, 0, dflag);
  };
  auto beta_step = [&](const u16* Th, const u16* Tl, const void* bias, int t) {
    gemm_k<128, 7, 0, 0><<<dim3(H_ / 128, GY), 256, 0, stream>>>(
        delta_, T_ * I_, t * I_, I_, nullptr, nullptr, nullptr, 0, 0, nullptr, 0,
        Th, Tl, I_, bias, nullptr, nullptr, nullptr, Beta1, H_, nullptr, 0, dflag);
  };

  // ---- encoder scan ----
  if (fullT) beta_all(eWtdT, eWtdL, ebtd);
  for (int t = 0; t < T_; ++t) {
    const float* Bet;
    int bstr;
    if (fullT) { Bet = BetaT + (size_t)t * H_; bstr = T_ * H_; }
    else { beta_step(eWtdT, eWtdL, ebtd, t); Bet = Beta1; bstr = H_; }
    if (xinT)
      gemm_k<128, 2, 2, 1><<<dim3((2 * H_) / 128, GY), 256, 0, stream>>>(
          Hb, H_, 0, H_, Xin, nullptr, nullptr, T_ * I_, t * I_, Bet, bstr,
          eWrmT, eWrmL, H_ + I_, ebr, ebmu, Hb, nullptr, RH, H_, MUb, 0, dflag);
    else
      gemm_k<128, 2, 2, 2><<<dim3((2 * H_) / 128, GY), 256, 0, stream>>>(
          Hb, H_, 0, H_, x_, mask_, noise_, T_ * I_, t * I_, Bet, bstr,
          eWrmT, eWrmL, H_ + I_, ebr, ebmu, Hb, nullptr, RH, H_, MUb, 0, dflag);
    if (xinT)
      gemm_k<64, 3, 1, 1><<<dim3(H_ / 64, GY), 256, 0, stream>>>(
          RH, H_, 0, H_, Xin, nullptr, nullptr, T_ * I_, t * I_, Bet, bstr,
          eWhhT, eWhhL, H_ + I_, ebhh, nullptr, Hb, MUb, Hb, H_, nullptr, 0, dflag);
    else
      gemm_k<64, 3, 1, 2><<<dim3(H_ / 64, GY), 256, 0, stream>>>(
          RH, H_, 0, H_, x_, mask_, noise_, T_ * I_, t * I_, Bet, bstr,
          eWhhT, eWhhL, H_ + I_, ebhh, nullptr, Hb, MUb, Hb, H_, nullptr, 0, dflag);
  }

  // ---- latent: z = h@zW+zb (into RH) ; dec_in = z@diW+dib (into Xt) ----
  gemm_k<128, 0, 1, 0><<<dim3(H_ / 128, GY), 256, 0, stream>>>(
      Hb, H_, 0, H_, nullptr, nullptr, nullptr, 0, 0, nullptr, 0,
      zWT, zWL, H_, zb, nullptr, nullptr, nullptr, RH, H_, nullptr, 0, dflag);
  gemm_k<128, 0, 1, 0><<<dim3(I_ / 128, GY), 256, 0, stream>>>(
      RH, H_, 0, H_, nullptr, nullptr, nullptr, 0, 0, nullptr, 0,
      diWT, diWL, H_, dib, nullptr, nullptr, nullptr, Xt, I_, nullptr, 0, dflag);
  zero_f32<<<(B_ * H_) / 256, 256, 0, stream>>>(Hb, B_ * H_);

  // ---- decoder scan ----
  if (fullT) beta_all(dWtdT, dWtdL, dbtd);
  for (int t = 0; t < T_; ++t) {
    const float* Bet;
    int bstr;
    if (fullT) { Bet = BetaT + (size_t)t * H_; bstr = T_ * H_; }
    else { beta_step(dWtdT, dWtdL, dbtd, t); Bet = Beta1; bstr = H_; }
    gemm_k<128, 2, 2, 1><<<dim3((2 * H_) / 128, GY), 256, 0, stream>>>(
        Hb, H_, 0, H_, Xt, nullptr, nullptr, I_, 0, Bet, bstr,
        dWrmT, dWrmL, H_ + I_, dbr, dbmu, Hb, nullptr, RH, H_, MUb, 0, dflag);
    gemm_k<64, 3, 1, 1><<<dim3(H_ / 64, GY), 256, 0, stream>>>(
        RH, H_, 0, H_, Xt, nullptr, nullptr, I_, 0, Bet, bstr,
        dWhhT, dWhhL, H_ + I_, dbhh, nullptr, Hb, MUb, Hb, H_, nullptr, 0, dflag);
    gemm_k<64, 5, 1, 0><<<dim3(I_ / 64, GY), 256, 0, stream>>>(
        Hb, H_, 0, H_, nullptr, nullptr, nullptr, 0, 0, nullptr, 0,
        rWT, rWL, H_, rb, nullptr, nullptr, nullptr, Xt, I_, d_out, t, dflag);
  }
}

// Round 2
// 20114.252 us; speedup vs baseline: 1.1742x; 1.1742x over previous
//
#include <hip/hip_runtime.h>
#include <cstdint>
#include <cstddef>

#define B_ 1024
#define T_ 96
#define I_ 256
#define H_ 1024

typedef unsigned short u16;
typedef __attribute__((ext_vector_type(8))) short short8;
typedef __attribute__((ext_vector_type(4))) float f32x4;
typedef __attribute__((ext_vector_type(4))) unsigned int u32x4;

__device__ __forceinline__ float bf2f(u16 u) {
  union { unsigned int i; float f; } v;
  v.i = ((unsigned int)u) << 16;
  return v.f;
}
__device__ __forceinline__ u16 f2bf(float f) {
  union { float f; unsigned int i; } v;
  v.f = f;
  unsigned int u = v.i;
  return (u16)((u + 0x7FFFu + ((u >> 16) & 1u)) >> 16);
}

// ---------------------------------------------------------------------------
// dtype detector: bf16 N(0,1) data has no u16 with exponent field >= 0xC0;
// fp32 data read as u16 has ~25% such words in the low halves. 0=bf16, 1=fp32.
__global__ void detect_dtype(const u16* __restrict__ xs, int* __restrict__ flag) {
  __shared__ int cnt;
  if (threadIdx.x == 0) cnt = 0;
  __syncthreads();
  int c = 0;
  for (int i = threadIdx.x; i < 8192; i += 256) {
    int e = (xs[i] >> 7) & 0xFF;
    if (e >= 0xC0) ++c;
  }
  atomicAdd(&cnt, c);
  __syncthreads();
  if (threadIdx.x == 0) *flag = (cnt > 32) ? 1 : 0;
}

__global__ void zero_f32(float* __restrict__ p, int n) {
  int i = blockIdx.x * 256 + threadIdx.x;
  if (i < n) p[i] = 0.f;
}

// weight transpose [K][N] -> hi/lo bf16 planes [N][K]; input dtype per flag
__global__ void transpose_w(const void* __restrict__ W, u16* __restrict__ Th,
                            u16* __restrict__ Tl, int K, int N,
                            const int* __restrict__ dflag) {
  __shared__ float tile[32][33];
  const int f = *dflag;
  int n0 = blockIdx.x * 32, k0 = blockIdx.y * 32;
  int tx = threadIdx.x, ty = threadIdx.y;
#pragma unroll
  for (int i = ty; i < 32; i += 8) {
    size_t o = (size_t)(k0 + i) * N + n0 + tx;
    tile[i][tx] = f ? ((const float*)W)[o] : bf2f(((const u16*)W)[o]);
  }
  __syncthreads();
#pragma unroll
  for (int i = ty; i < 32; i += 8) {
    float v = tile[tx][i];
    u16 h = f2bf(v);
    size_t o = (size_t)(n0 + i) * K + k0 + tx;
    Th[o] = h;
    Tl[o] = f2bf(v - bf2f(h));
  }
}

// xin = x*mask+noise -> hi/lo bf16 planes (bit-identical split to in-GEMM)
__global__ void make_xin_planes(const void* __restrict__ x, const void* __restrict__ m,
                                const void* __restrict__ nz, u16* __restrict__ oh,
                                u16* __restrict__ ol, const int* __restrict__ dflag) {
  const int f = *dflag;
  size_t i = ((size_t)blockIdx.x * 256 + threadIdx.x) * 8;
  float v[8];
  if (f) {
    const float* xp = (const float*)x + i;
    const float* mp = (const float*)m + i;
    const float* np = (const float*)nz + i;
    f32x4 x0 = *(const f32x4*)xp, x1 = *(const f32x4*)(xp + 4);
    f32x4 m0 = *(const f32x4*)mp, m1 = *(const f32x4*)(mp + 4);
    f32x4 n0 = *(const f32x4*)np, n1 = *(const f32x4*)(np + 4);
#pragma unroll
    for (int j = 0; j < 4; ++j) {
      v[j] = x0[j] * m0[j] + n0[j];
      v[j + 4] = x1[j] * m1[j] + n1[j];
    }
  } else {
    union { u32x4 q; u16 s[8]; } ux, um, un;
    ux.q = *(const u32x4*)((const u16*)x + i);
    um.q = *(const u32x4*)((const u16*)m + i);
    un.q = *(const u32x4*)((const u16*)nz + i);
#pragma unroll
    for (int j = 0; j < 8; ++j) v[j] = bf2f(ux.s[j]) * bf2f(um.s[j]) + bf2f(un.s[j]);
  }
  union { u16 s[8]; u32x4 q; } ph, pl;
#pragma unroll
  for (int j = 0; j < 8; ++j) {
    u16 h = f2bf(v[j]);
    ph.s[j] = h;
    pl.s[j] = f2bf(v[j] - bf2f(h));
  }
  *(u32x4*)(oh + i) = ph.q;
  *(u32x4*)(ol + i) = pl.q;
}

// reg epilogue: v = tanh(P+b); Xt planes + out (dtype per flag); P=0
__global__ void ew_reg(float* __restrict__ P, const void* __restrict__ bias,
                       u16* __restrict__ XtH, u16* __restrict__ XtL,
                       void* __restrict__ out, int t,
                       const int* __restrict__ dflag) {
  const int f = *dflag;
  int i = blockIdx.x * 256 + threadIdx.x;  // B_*I_ total
  int col = i & (I_ - 1);
  int row = i >> 8;
  float bv = f ? ((const float*)bias)[col] : bf2f(((const u16*)bias)[col]);
  float v = tanhf(P[i] + bv);
  u16 h = f2bf(v);
  XtH[i] = h;
  XtL[i] = f2bf(v - bf2f(h));
  size_t oidx = (size_t)row * (T_ * I_) + (size_t)t * I_ + col;
  if (f) ((float*)out)[oidx] = v;
  else ((u16*)out)[oidx] = f2bf(v);
  P[i] = 0.f;
}

// ---------------------------------------------------------------------------
// Split MFMA GEMM.  Block tile 64 x BN, 256 threads (4 waves 2x2), 16x16x32
// bf16 MFMA, BK=32, 1-deep register prefetch.  A staged as hi/lo bf16 planes;
// B pre-transposed hi/lo planes [N][K] (lo skipped when inputs are bf16).
// AMODE: 0 = A external dtype-per-flag (A0,lda0,aoff0); bf16 -> raw copy
//        1 = part1 fp32 (A0), part2 fp32 (Ax,lda1,aoff1)
//        2 = part1 fp32 (A0), part2 fused x*mask+noise (Ax,Am,An)
//        3 = part1 planes (A0=hi,Al=lo), part2 planes (Ax=hi,Am=lo)
//        4 = part1 planes (A0=hi,Al=lo), part2 fused x*mask+noise
// EPI: 0 = store p+bias0 fp32              (dst0, dstr0)
//      1 = beta: planes(exp(-relu(p+b))*src0)   (dph/dpl; src0=Hb)
//      2 = r/mu: col<H planes(sig*recon(sp)); else mu->dst1  (dph/dpl, dst1)
//      3 = h=(1-mu)*recon(sp)+mu*tanh(p+b) (dst0=Hb; src1=MU; sph/spl=Hs)
//      4 = split-K partial atomicAdd       (dst0, dstr0)
//      6 = planes(p+bias0)                 (dph/dpl, dstr0)
template <int BN, int EPI, int AMODE>
__global__ __launch_bounds__(256) void gemm_k(
    const void* __restrict__ A0, const void* __restrict__ Al, int lda0,
    int aoff0, int K0,
    const void* __restrict__ Ax, const void* __restrict__ Am,
    const void* __restrict__ An, int lda1, int aoff1,
    const u16* __restrict__ BTh, const u16* __restrict__ BTl, int K, int Ksl,
    const void* __restrict__ bias0, const void* __restrict__ bias1,
    const float* __restrict__ src0, const float* __restrict__ src1,
    const u16* __restrict__ sph, const u16* __restrict__ spl,
    float* __restrict__ dst0, int dstr0, float* __restrict__ dst1,
    u16* __restrict__ dph, u16* __restrict__ dpl,
    const int* __restrict__ dflag) {
  __shared__ __align__(16) u16 As_hi[64][40];
  __shared__ __align__(16) u16 As_lo[64][40];
  __shared__ __align__(16) u16 Bs_hi[BN][40];
  __shared__ __align__(16) u16 Bs_lo[BN][40];

  const int f = *dflag;                    // uniform: 0=bf16 inputs, 1=fp32
  const bool alo = (AMODE != 0) || f;      // A-lo plane active?

  const int tid = threadIdx.x;
  const int m0 = blockIdx.y * 64;
  const int n0 = blockIdx.x * BN;
  const int kbeg = blockIdx.z * Ksl;
  const int kend = kbeg + Ksl;

  const int w = tid >> 6;
  const int lane = tid & 63;
  const int wx = w & 1, wy = w >> 1;
  const int lr = lane & 15, q = lane >> 4;
  constexpr int NB = BN / 32;

  f32x4 acc[2][NB];
#pragma unroll
  for (int mb = 0; mb < 2; ++mb)
#pragma unroll
    for (int nb = 0; nb < NB; ++nb)
      acc[mb][nb] = (f32x4){0.f, 0.f, 0.f, 0.f};

  const int ar = tid >> 2, ac8 = (tid & 3) * 8;
  const int bn = (BN == 128) ? (tid >> 1) : (tid >> 2);
  const int bc = (BN == 128) ? ((tid & 1) * 16) : ((tid & 3) * 8);

  float av[8];                   // prefetched A as fp32 (convert paths)
  u32x4 pah, pal;                // prefetched A planes (copy paths)
  u32x4 pbh0, pbh1, pbl0, pbl1;  // prefetched B hi/lo

  auto load_chunk = [&](int kc) {
    // ---- A operand ----
    if (AMODE == 0) {
      size_t o = (size_t)(m0 + ar) * lda0 + aoff0 + kc + ac8;
      if (f) {
        f32x4 t0 = *(const f32x4*)((const float*)A0 + o);
        f32x4 t1 = *(const f32x4*)((const float*)A0 + o + 4);
#pragma unroll
        for (int j = 0; j < 4; ++j) { av[j] = t0[j]; av[j + 4] = t1[j]; }
      } else {
        pah = *(const u32x4*)((const u16*)A0 + o);  // raw bf16 copy
      }
    } else if (kc < K0) {
      size_t o = (size_t)(m0 + ar) * lda0 + aoff0 + kc + ac8;
      if (AMODE == 1 || AMODE == 2) {
        f32x4 t0 = *(const f32x4*)((const float*)A0 + o);
        f32x4 t1 = *(const f32x4*)((const float*)A0 + o + 4);
#pragma unroll
        for (int j = 0; j < 4; ++j) { av[j] = t0[j]; av[j + 4] = t1[j]; }
      } else {  // 3,4: pre-split planes
        pah = *(const u32x4*)((const u16*)A0 + o);
        pal = *(const u32x4*)((const u16*)Al + o);
      }
    } else {
      int kk = kc - K0;
      size_t o = (size_t)(m0 + ar) * lda1 + aoff1 + kk + ac8;
      if (AMODE == 1) {
        f32x4 t0 = *(const f32x4*)((const float*)Ax + o);
        f32x4 t1 = *(const f32x4*)((const float*)Ax + o + 4);
#pragma unroll
        for (int j = 0; j < 4; ++j) { av[j] = t0[j]; av[j + 4] = t1[j]; }
      } else if (AMODE == 3) {  // planes
        pah = *(const u32x4*)((const u16*)Ax + o);
        pal = *(const u32x4*)((const u16*)Am + o);
      } else {  // 2,4: fused x*mask+noise
        if (f) {
          const float* xp = (const float*)Ax + o;
          const float* mp = (const float*)Am + o;
          const float* np = (const float*)An + o;
          f32x4 x0 = *(const f32x4*)xp, x1 = *(const f32x4*)(xp + 4);
          f32x4 m0v = *(const f32x4*)mp, m1v = *(const f32x4*)(mp + 4);
          f32x4 n0v = *(const f32x4*)np, n1v = *(const f32x4*)(np + 4);
#pragma unroll
          for (int j = 0; j < 4; ++j) {
            av[j] = x0[j] * m0v[j] + n0v[j];
            av[j + 4] = x1[j] * m1v[j] + n1v[j];
          }
        } else {
          union { u32x4 v; u16 s[8]; } ux, um, un;
          ux.v = *(const u32x4*)((const u16*)Ax + o);
          um.v = *(const u32x4*)((const u16*)Am + o);
          un.v = *(const u32x4*)((const u16*)An + o);
#pragma unroll
          for (int j = 0; j < 8; ++j)
            av[j] = bf2f(ux.s[j]) * bf2f(um.s[j]) + bf2f(un.s[j]);
        }
      }
    }
    // ---- B operand ----
    const u16* Bph = BTh + (size_t)(n0 + bn) * K + kc + bc;
    pbh0 = *(const u32x4*)Bph;
    if (BN == 128) pbh1 = *(const u32x4*)(Bph + 8);
    if (f) {
      const u16* Bpl = BTl + (size_t)(n0 + bn) * K + kc + bc;
      pbl0 = *(const u32x4*)Bpl;
      if (BN == 128) pbl1 = *(const u32x4*)(Bpl + 8);
    }
  };

  auto drain = [&](int kc) {
    // which A path produced this chunk?
    bool plane = (AMODE == 3) || (AMODE == 4 && kc < K0) || (AMODE == 0 && !f);
    if (plane) {
      *(u32x4*)&As_hi[ar][ac8] = pah;
      if (AMODE != 0) *(u32x4*)&As_lo[ar][ac8] = pal;
    } else {
      union { u16 s[8]; u32x4 v; } ph, pl;
#pragma unroll
      for (int j = 0; j < 8; ++j) {
        u16 h = f2bf(av[j]);
        ph.s[j] = h;
        pl.s[j] = f2bf(av[j] - bf2f(h));
      }
      *(u32x4*)&As_hi[ar][ac8] = ph.v;
      if (alo) *(u32x4*)&As_lo[ar][ac8] = pl.v;
    }
    *(u32x4*)&Bs_hi[bn][bc] = pbh0;
    if (BN == 128) *(u32x4*)&Bs_hi[bn][bc + 8] = pbh1;
    if (f) {
      *(u32x4*)&Bs_lo[bn][bc] = pbl0;
      if (BN == 128) *(u32x4*)&Bs_lo[bn][bc + 8] = pbl1;
    }
  };

  load_chunk(kbeg);

  for (int kc = kbeg; kc < kend; kc += 32) {
    drain(kc);
    __syncthreads();

    if (kc + 32 < kend) load_chunk(kc + 32);  // in flight during compute

    short8 ah[2], al[2];
#pragma unroll
    for (int mb = 0; mb < 2; ++mb) {
      ah[mb] = *(const short8*)&As_hi[wy * 32 + mb * 16 + lr][q * 8];
      if (alo) al[mb] = *(const short8*)&As_lo[wy * 32 + mb * 16 + lr][q * 8];
    }
#pragma unroll
    for (int nb = 0; nb < NB; ++nb) {
      short8 bh = *(const short8*)&Bs_hi[wx * (BN / 2) + nb * 16 + lr][q * 8];
#pragma unroll
      for (int mb = 0; mb < 2; ++mb) {
        acc[mb][nb] = __builtin_amdgcn_mfma_f32_16x16x32_bf16(ah[mb], bh, acc[mb][nb], 0, 0, 0);
        if (alo)
          acc[mb][nb] = __builtin_amdgcn_mfma_f32_16x16x32_bf16(al[mb], bh, acc[mb][nb], 0, 0, 0);
      }
      if (f) {
        short8 bl = *(const short8*)&Bs_lo[wx * (BN / 2) + nb * 16 + lr][q * 8];
#pragma unroll
        for (int mb = 0; mb < 2; ++mb)
          acc[mb][nb] = __builtin_amdgcn_mfma_f32_16x16x32_bf16(ah[mb], bl, acc[mb][nb], 0, 0, 0);
      }
    }
    __syncthreads();
  }

  auto bget = [&](const void* b, int c) -> float {
    return f ? ((const float*)b)[c] : bf2f(((const u16*)b)[c]);
  };
  auto pstore = [&](size_t ix, float v) {
    u16 h = f2bf(v);
    dph[ix] = h;
    dpl[ix] = f2bf(v - bf2f(h));
  };

  // epilogue: D row = q*4+r, col = lane&15 (m89-verified C/D layout)
#pragma unroll
  for (int mb = 0; mb < 2; ++mb) {
#pragma unroll
    for (int nb = 0; nb < NB; ++nb) {
#pragma unroll
      for (int r = 0; r < 4; ++r) {
        int row = m0 + wy * 32 + mb * 16 + q * 4 + r;
        int col = n0 + wx * (BN / 2) + nb * 16 + lr;
        float p = acc[mb][nb][r];
        if (EPI == 0) {
          dst0[(size_t)row * dstr0 + col] = p + bget(bias0, col);
        } else if (EPI == 1) {  // beta: Hs planes = exp(-relu(p+b)) * Hb
          float beta = expf(-fmaxf(p + bget(bias0, col), 0.f));
          pstore((size_t)row * H_ + col, beta * src0[(size_t)row * H_ + col]);
        } else if (EPI == 2) {  // r/mu gates
          if (col < H_) {
            size_t ix = (size_t)row * H_ + col;
            float rr = 1.f / (1.f + expf(-(p + bget(bias0, col))));
            float hs = bf2f(sph[ix]) + bf2f(spl[ix]);
            pstore(ix, rr * hs);
          } else {
            int c = col - H_;
            float mu = 1.f / (1.f + expf(-(p + bget(bias1, c))));
            dst1[(size_t)row * H_ + c] = mu;
          }
        } else if (EPI == 3) {  // h = (1-mu)*hs + mu*tanh(p+b)
          size_t ix = (size_t)row * H_ + col;
          float hh = tanhf(p + bget(bias0, col));
          float mu = src1[ix];
          float hs = bf2f(sph[ix]) + bf2f(spl[ix]);
          dst0[ix] = (1.f - mu) * hs + mu * hh;
        } else if (EPI == 4) {  // split-K partial
          atomicAdd(&dst0[(size_t)row * dstr0 + col], p);
        } else if (EPI == 6) {  // planes(p+bias)
          pstore((size_t)row * dstr0 + col, p + bget(bias0, col));
        }
      }
    }
  }
}

// ---------------------------------------------------------------------------
extern "C" void kernel_launch(void* const* d_in, const int* in_sizes, int n_in,
                              void* d_out, int out_size, void* d_ws, size_t ws_size,
                              hipStream_t stream) {
  const void* x_ = d_in[0];
  const void* mask_ = d_in[1];
  const void* delta_ = d_in[2];
  const void* noise_ = d_in[3];
  const void* eWtd = d_in[4];
  const void* ebtd = d_in[5];
  const void* eWr = d_in[6];
  const void* ebr = d_in[7];
  const void* eWmu = d_in[8];
  const void* ebmu = d_in[9];
  const void* eWhh = d_in[10];
  const void* ebhh = d_in[11];
  const void* zW = d_in[12];
  const void* zb = d_in[13];
  const void* diW = d_in[14];
  const void* dib = d_in[15];
  const void* dWtd = d_in[16];
  const void* dbtd = d_in[17];
  const void* dWr = d_in[18];
  const void* dbr = d_in[19];
  const void* dWmu = d_in[20];
  const void* dbmu = d_in[21];
  const void* dWhh = d_in[22];
  const void* dbhh = d_in[23];
  const void* rW = d_in[24];
  const void* rb = d_in[25];

  char* ws = (char*)d_ws;
  size_t off = 0;
  auto alloc = [&](size_t bytes) -> char* {
    char* p = ws + off;
    off = (off + bytes + 255) & ~(size_t)255;
    return p;
  };
  int* dflag = (int*)alloc(256);
  float* Hb = (float*)alloc((size_t)B_ * H_ * 4);
  float* MUb = (float*)alloc((size_t)B_ * H_ * 4);
  float* Z = (float*)alloc((size_t)B_ * H_ * 4);
  float* Pr = (float*)alloc((size_t)B_ * I_ * 4);
  u16* HsH = (u16*)alloc((size_t)B_ * H_ * 2);
  u16* HsL = (u16*)alloc((size_t)B_ * H_ * 2);
  u16* RHH = (u16*)alloc((size_t)B_ * H_ * 2);
  u16* RHL = (u16*)alloc((size_t)B_ * H_ * 2);
  u16* XtH = (u16*)alloc((size_t)B_ * I_ * 2);
  u16* XtL = (u16*)alloc((size_t)B_ * I_ * 2);
  auto wpair = [&](size_t elems, u16** lo) -> u16* {
    u16* hi = (u16*)alloc(elems * 2);
    *lo = (u16*)alloc(elems * 2);
    return hi;
  };
  u16 *eWtdL, *eWrmL, *eWhhL, *zWL, *diWL, *dWtdL, *dWrmL, *dWhhL, *rWL;
  u16* eWtdT = wpair((size_t)H_ * I_, &eWtdL);
  u16* eWrmT = wpair((size_t)2 * H_ * (H_ + I_), &eWrmL);
  u16* eWhhT = wpair((size_t)H_ * (H_ + I_), &eWhhL);
  u16* zWT = wpair((size_t)H_ * H_, &zWL);
  u16* diWT = wpair((size_t)I_ * H_, &diWL);
  u16* dWtdT = wpair((size_t)H_ * I_, &dWtdL);
  u16* dWrmT = wpair((size_t)2 * H_ * (H_ + I_), &dWrmL);
  u16* dWhhT = wpair((size_t)H_ * (H_ + I_), &dWhhL);
  u16* rWT = wpair((size_t)I_ * H_, &rWL);
  // ws-gated xin planes (~100 MB)
  u16* XinH = (u16*)alloc((size_t)B_ * T_ * I_ * 2);
  u16* XinL = (u16*)alloc((size_t)B_ * T_ * I_ * 2);
  const bool xinT = ws_size >= off;

  // prolog: detect dtype, zero state + split-K accumulator, transpose weights
  detect_dtype<<<1, 256, 0, stream>>>((const u16*)x_, dflag);
  zero_f32<<<(B_ * H_) / 256, 256, 0, stream>>>(Hb, B_ * H_);
  zero_f32<<<(B_ * I_) / 256, 256, 0, stream>>>(Pr, B_ * I_);

  auto tr = [&](const void* W, u16* Th, u16* Tl, int K, int N) {
    transpose_w<<<dim3(N / 32, K / 32), dim3(32, 8), 0, stream>>>(W, Th, Tl, K, N, dflag);
  };
  tr(eWtd, eWtdT, eWtdL, I_, H_);
  tr(eWr, eWrmT, eWrmL, H_ + I_, H_);
  tr(eWmu, eWrmT + (size_t)H_ * (H_ + I_), eWrmL + (size_t)H_ * (H_ + I_), H_ + I_, H_);
  tr(eWhh, eWhhT, eWhhL, H_ + I_, H_);
  tr(zW, zWT, zWL, H_, H_);
  tr(diW, diWT, diWL, H_, I_);
  tr(dWtd, dWtdT, dWtdL, I_, H_);
  tr(dWr, dWrmT, dWrmL, H_ + I_, H_);
  tr(dWmu, dWrmT + (size_t)H_ * (H_ + I_), dWrmL + (size_t)H_ * (H_ + I_), H_ + I_, H_);
  tr(dWhh, dWhhT, dWhhL, H_ + I_, H_);
  tr(rW, rWT, rWL, H_, I_);

  if (xinT)
    make_xin_planes<<<(B_ * T_ * I_) / (256 * 8), 256, 0, stream>>>(
        x_, mask_, noise_, XinH, XinL, dflag);

  const int GY = B_ / 64;  // 16

  // ---- encoder scan ----
  for (int t = 0; t < T_; ++t) {
    // beta: Hs planes = exp(-relu(delta@Wtd+b)) * Hb
    gemm_k<64, 1, 0><<<dim3(H_ / 64, GY, 1), 256, 0, stream>>>(
        delta_, nullptr, T_ * I_, t * I_, I_, nullptr, nullptr, nullptr, 0, 0,
        eWtdT, eWtdL, I_, I_, ebtd, nullptr, Hb, nullptr, nullptr, nullptr,
        nullptr, 0, nullptr, HsH, HsL, dflag);
    // r/mu
    if (xinT)
      gemm_k<128, 2, 3><<<dim3((2 * H_) / 128, GY, 1), 256, 0, stream>>>(
          HsH, HsL, H_, 0, H_, XinH, XinL, nullptr, T_ * I_, t * I_,
          eWrmT, eWrmL, H_ + I_, H_ + I_, ebr, ebmu, nullptr, nullptr, HsH, HsL,
          nullptr, 0, MUb, RHH, RHL, dflag);
    else
      gemm_k<128, 2, 4><<<dim3((2 * H_) / 128, GY, 1), 256, 0, stream>>>(
          HsH, HsL, H_, 0, H_, x_, mask_, noise_, T_ * I_, t * I_,
          eWrmT, eWrmL, H_ + I_, H_ + I_, ebr, ebmu, nullptr, nullptr, HsH, HsL,
          nullptr, 0, MUb, RHH, RHL, dflag);
    // hh + h-update
    if (xinT)
      gemm_k<64, 3, 3><<<dim3(H_ / 64, GY, 1), 256, 0, stream>>>(
          RHH, RHL, H_, 0, H_, XinH, XinL, nullptr, T_ * I_, t * I_,
          eWhhT, eWhhL, H_ + I_, H_ + I_, ebhh, nullptr, nullptr, MUb, HsH, HsL,
          Hb, H_, nullptr, nullptr, nullptr, dflag);
    else
      gemm_k<64, 3, 4><<<dim3(H_ / 64, GY, 1), 256, 0, stream>>>(
          RHH, RHL, H_, 0, H_, x_, mask_, noise_, T_ * I_, t * I_,
          eWhhT, eWhhL, H_ + I_, H_ + I_, ebhh, nullptr, nullptr, MUb, HsH, HsL,
          Hb, H_, nullptr, nullptr, nullptr, dflag);
  }

  // ---- latent: z = h@zW+zb (fp32 Z) ; dec_in = z@diW+dib (Xt planes) ----
  gemm_k<128, 0, 1><<<dim3(H_ / 128, GY, 1), 256, 0, stream>>>(
      Hb, nullptr, H_, 0, H_, nullptr, nullptr, nullptr, 0, 0,
      zWT, zWL, H_, H_, zb, nullptr, nullptr, nullptr, nullptr, nullptr,
      Z, H_, nullptr, nullptr, nullptr, dflag);
  gemm_k<128, 6, 1><<<dim3(I_ / 128, GY, 1), 256, 0, stream>>>(
      Z, nullptr, H_, 0, H_, nullptr, nullptr, nullptr, 0, 0,
      diWT, diWL, H_, H_, dib, nullptr, nullptr, nullptr, nullptr, nullptr,
      nullptr, I_, nullptr, XtH, XtL, dflag);
  zero_f32<<<(B_ * H_) / 256, 256, 0, stream>>>(Hb, B_ * H_);

  // ---- decoder scan ----
  for (int t = 0; t < T_; ++t) {
    gemm_k<64, 1, 0><<<dim3(H_ / 64, GY, 1), 256, 0, stream>>>(
        delta_, nullptr, T_ * I_, t * I_, I_, nullptr, nullptr, nullptr, 0, 0,
        dWtdT, dWtdL, I_, I_, dbtd, nullptr, Hb, nullptr, nullptr, nullptr,
        nullptr, 0, nullptr, HsH, HsL, dflag);
    gemm_k<128, 2, 3><<<dim3((2 * H_) / 128, GY, 1), 256, 0, stream>>>(
        HsH, HsL, H_, 0, H_, XtH, XtL, nullptr, I_, 0,
        dWrmT, dWrmL, H_ + I_, H_ + I_, dbr, dbmu, nullptr, nullptr, HsH, HsL,
        nullptr, 0, MUb, RHH, RHL, dflag);
    gemm_k<64, 3, 3><<<dim3(H_ / 64, GY, 1), 256, 0, stream>>>(
        RHH, RHL, H_, 0, H_, XtH, XtL, nullptr, I_, 0,
        dWhhT, dWhhL, H_ + I_, H_ + I_, dbhh, nullptr, nullptr, MUb, HsH, HsL,
        Hb, H_, nullptr, nullptr, nullptr, dflag);
    gemm_k<64, 4, 1><<<dim3(I_ / 64, GY, 4), 256, 0, stream>>>(
        Hb, nullptr, H_, 0, H_, nullptr, nullptr, nullptr, 0, 0,
        rWT, rWL, H_, H_ / 4, nullptr, nullptr, nullptr, nullptr, nullptr, nullptr,
        Pr, I_, nullptr, nullptr, nullptr, dflag);
    ew_reg<<<(B_ * I_) / 256, 256, 0, stream>>>(Pr, rb, XtH, XtL, d_out, t, dflag);
  }
}